// Round 1
// baseline (194.897 us; speedup 1.0000x reference)
//
#include <hip/hip_runtime.h>

#define B 8
#define C 64
#define CR 8
#define HW 65536   // 256*256
#define HWF 8192   // HW/8 (folded spatial length)
#define SPLIT 64
#define CHUNK 128  // HWF / SPLIT

__device__ __forceinline__ void fma4(float4& a, float w, const float4& v) {
  a.x = fmaf(w, v.x, a.x); a.y = fmaf(w, v.y, a.y);
  a.z = fmaf(w, v.z, a.z); a.w = fmaf(w, v.w, a.w);
}

// ---------------- K1: fused q/k 1x1 conv -------------------------------------
// rgb (B,64,HW) -> qbuf,kbuf (B,8,HW). 256 thr, 2 positions/thread (float2),
// grid (HW/512, B) = (128,8) -> 16 waves/CU for latency hiding. Memory-bound.
__global__ __launch_bounds__(256) void k_qkconv(
    const float* __restrict__ rgb,
    const float* __restrict__ Wq, const float* __restrict__ bq,
    const float* __restrict__ Wk, const float* __restrict__ bk,
    float* __restrict__ qbuf, float* __restrict__ kbuf) {
  __shared__ float wqT[64][8];   // [ch][o] so per-ch read is 2x ds_read_b128
  __shared__ float wkT[64][8];
  __shared__ float bqs[8], bks[8];
  int tid = threadIdx.x;
  for (int i = tid; i < 512; i += 256) {
    int o = i >> 6, ch = i & 63;
    wqT[ch][o] = Wq[i];
    wkT[ch][o] = Wk[i];
  }
  if (tid < 8) { bqs[tid] = bq[tid]; bks[tid] = bk[tid]; }
  __syncthreads();

  int b = blockIdx.y;
  int s = blockIdx.x * 512 + tid * 2;
  const float* rp = rgb + (size_t)b * C * HW + s;
  float2 aq[8], ak[8];
#pragma unroll
  for (int o = 0; o < 8; ++o) {
    aq[o] = make_float2(bqs[o], bqs[o]);
    ak[o] = make_float2(bks[o], bks[o]);
  }
#pragma unroll 8
  for (int ch = 0; ch < 64; ++ch) {
    float2 v = *reinterpret_cast<const float2*>(rp + (size_t)ch * HW);
#pragma unroll
    for (int o = 0; o < 8; ++o) {
      float wq = wqT[ch][o], wk = wkT[ch][o];
      aq[o].x = fmaf(wq, v.x, aq[o].x); aq[o].y = fmaf(wq, v.y, aq[o].y);
      ak[o].x = fmaf(wk, v.x, ak[o].x); ak[o].y = fmaf(wk, v.y, ak[o].y);
    }
  }
#pragma unroll
  for (int o = 0; o < 8; ++o) {
    *reinterpret_cast<float2*>(qbuf + ((size_t)b * CR + o) * HW + s) = aq[o];
    *reinterpret_cast<float2*>(kbuf + ((size_t)b * CR + o) * HW + s) = ak[o];
  }
}

// ---------------- K2: energy partials (split-K Gram) -------------------------
// q,k viewed (B,64,8192). Block = (batch, split): 64x64 partial Gram over a
// 128-wide n-chunk. 128 thr, 8x4 register tile. LDS tiles are XOR-swizzled
// (float4 slot ^ (row>>2)&7) so the 16-address d-tile ds_read_b128 lands on
// 8 distinct bank groups (2-way = free) instead of 8/16-way with padding.
__global__ __launch_bounds__(128) void k_energy(
    const float* __restrict__ qbuf, const float* __restrict__ kbuf,
    float* __restrict__ part) {
  __shared__ float qs[64 * 128];
  __shared__ float ks[64 * 128];
  int tid = threadIdx.x;
  int b = blockIdx.y, sp = blockIdx.x;
  int n0 = sp * CHUNK;
  const float* qb = qbuf + (size_t)b * (CR * HW) + n0;
  const float* kb = kbuf + (size_t)b * (CR * HW) + n0;
  for (int i = tid; i < 64 * 32; i += 128) {
    int row = i >> 5, n4 = i & 31;
    float4 qv = *reinterpret_cast<const float4*>(qb + row * HWF + n4 * 4);
    float4 kv = *reinterpret_cast<const float4*>(kb + row * HWF + n4 * 4);
    int off = (row << 7) + ((n4 ^ ((row >> 2) & 7)) << 2);
    *reinterpret_cast<float4*>(&qs[off]) = qv;
    *reinterpret_cast<float4*>(&ks[off]) = kv;
  }
  __syncthreads();

  int c8 = tid >> 4;   // 0..7  (8 q-rows each)
  int d4 = tid & 15;   // 0..15 (4 k-rows each)
  float acc[8][4];
#pragma unroll
  for (int i = 0; i < 8; ++i)
#pragma unroll
    for (int j = 0; j < 4; ++j) acc[i][j] = 0.f;

#pragma unroll 2
  for (int n4 = 0; n4 < 32; ++n4) {
    float4 qv[8], kv[4];
#pragma unroll
    for (int cc = 0; cc < 8; ++cc) {
      int r = c8 * 8 + cc;
      qv[cc] = *reinterpret_cast<const float4*>(
          &qs[(r << 7) + ((n4 ^ ((r >> 2) & 7)) << 2)]);
    }
#pragma unroll
    for (int dd = 0; dd < 4; ++dd) {
      int r = d4 * 4 + dd;
      kv[dd] = *reinterpret_cast<const float4*>(
          &ks[(r << 7) + ((n4 ^ ((r >> 2) & 7)) << 2)]);
    }
#pragma unroll
    for (int cc = 0; cc < 8; ++cc)
#pragma unroll
      for (int dd = 0; dd < 4; ++dd) {
        acc[cc][dd] = fmaf(qv[cc].x, kv[dd].x,
                      fmaf(qv[cc].y, kv[dd].y,
                      fmaf(qv[cc].z, kv[dd].z,
                      fmaf(qv[cc].w, kv[dd].w, acc[cc][dd]))));
      }
  }
  // part[b][c*64+d][split] — split-contiguous so the reducer reads coalesced
#pragma unroll
  for (int cc = 0; cc < 8; ++cc)
#pragma unroll
    for (int dd = 0; dd < 4; ++dd) {
      int c = c8 * 8 + cc, d = d4 * 4 + dd;
      part[((size_t)b * 4096 + c * 64 + d) * SPLIT + sp] = acc[cc][dd];
    }
}

// ---------------- K3a: deterministic split-K reduction -----------------------
__global__ __launch_bounds__(256) void k_reduce(
    const float* __restrict__ part, float* __restrict__ energy) {
  int gid = blockIdx.x * 256 + threadIdx.x;   // 0..32767 = b*4096 + c*64 + d
  const float4* p = reinterpret_cast<const float4*>(part + (size_t)gid * SPLIT);
  float4 s = make_float4(0.f, 0.f, 0.f, 0.f);
#pragma unroll
  for (int i = 0; i < SPLIT / 4; ++i) {
    float4 v = p[i];
    s.x += v.x; s.y += v.y; s.z += v.z; s.w += v.w;
  }
  energy[gid] = (s.x + s.y) + (s.z + s.w);
}

// ---------------- K3b: softmax + fold into Wf = alpha*attn*Wv + I ------------
// softmax(max_d(e) - e) == exp(min_d(e) - e) / sum (the max-shift cancels).
// Writes WfT[b][ch][c] (transposed for K4's b128 reads) and cf = alpha*attn*bv.
__global__ __launch_bounds__(256) void k_attn_wf(
    const float* __restrict__ energy,
    const float* __restrict__ Wv, const float* __restrict__ bv,
    const float* __restrict__ alpha,
    float* __restrict__ wfT, float* __restrict__ cf) {
  __shared__ float es[64][65];   // +1 pad: row-strided reads spread banks
  __shared__ float at[64][65];
  __shared__ float wv[64 * 64];
  __shared__ float bvs[64];
  int tid = threadIdx.x;
  int b = blockIdx.x;
  const float* eb = energy + b * 4096;
  for (int i = tid; i < 4096; i += 256) {
    es[i >> 6][i & 63] = eb[i];
    wv[i] = Wv[i];
  }
  if (tid < 64) bvs[tid] = bv[tid];
  __syncthreads();
  float al = alpha[0];
  if (tid < 64) {
    int c = tid;
    float mn = es[c][0];
    for (int d = 1; d < 64; ++d) mn = fminf(mn, es[c][d]);
    float ssum = 0.f;
    for (int d = 0; d < 64; ++d) {
      float t = __expf(mn - es[c][d]);
      at[c][d] = t; ssum += t;
    }
    float inv = 1.f / ssum;   // ssum >= 1 (the min term is exp(0)), finite
    float cb = 0.f;
    for (int d = 0; d < 64; ++d) { at[c][d] *= inv; cb += at[c][d] * bvs[d]; }
    cf[b * 64 + c] = al * cb;
  }
  __syncthreads();
  for (int i = tid; i < 4096; i += 256) {
    int ch = i >> 6, c = i & 63;   // wave: ch uniform (broadcast), c = lane
    float s = 0.f;
    for (int d = 0; d < 64; ++d) s = fmaf(at[c][d], wv[d * 64 + ch], s);
    wfT[(size_t)b * 4096 + i] = al * s + (c == ch ? 1.f : 0.f);
  }
}

// ---------------- K4: streaming epilogue out = Wf*Y + cf ---------------------
// Per block: 128 positions x all 64 out-channels. Thread = (cg 0..7, pg 0..31):
// 8 channels x 4 positions, 32 FMA per (1 global b128 + 2 ds b128). Memory-
// bound target ~268 MB; compute 4.3 GF hides under it.
__global__ __launch_bounds__(256) void k_out(
    const float* __restrict__ y,
    const float* __restrict__ wfT, const float* __restrict__ cf,
    float* __restrict__ out) {
  __shared__ float wf[64 * 64];   // [ch][c]
  __shared__ float cfs[64];
  int tid = threadIdx.x;
  int b = blockIdx.y;
  for (int i = tid; i < 4096; i += 256) wf[i] = wfT[(size_t)b * 4096 + i];
  if (tid < 64) cfs[tid] = cf[b * 64 + tid];
  __syncthreads();

  int pg = tid & 31, cg = tid >> 5;
  int s = blockIdx.x * 128 + pg * 4;
  const float* yb = y + (size_t)b * (C * HW) + s;
  float4 acc[8];
#pragma unroll
  for (int cc = 0; cc < 8; ++cc) {
    float v = cfs[cg * 8 + cc];
    acc[cc] = make_float4(v, v, v, v);
  }
#pragma unroll 4
  for (int ch = 0; ch < 64; ++ch) {
    float4 yv = *reinterpret_cast<const float4*>(yb + (size_t)ch * HW);
    float4 w0 = *reinterpret_cast<const float4*>(&wf[ch * 64 + cg * 8]);
    float4 w1 = *reinterpret_cast<const float4*>(&wf[ch * 64 + cg * 8 + 4]);
    fma4(acc[0], w0.x, yv); fma4(acc[1], w0.y, yv);
    fma4(acc[2], w0.z, yv); fma4(acc[3], w0.w, yv);
    fma4(acc[4], w1.x, yv); fma4(acc[5], w1.y, yv);
    fma4(acc[6], w1.z, yv); fma4(acc[7], w1.w, yv);
  }
  float* ob = out + (size_t)b * (C * HW) + s;
#pragma unroll
  for (int cc = 0; cc < 8; ++cc)
    *reinterpret_cast<float4*>(ob + (size_t)(cg * 8 + cc) * HW) = acc[cc];
}

extern "C" void kernel_launch(void* const* d_in, const int* in_sizes, int n_in,
                              void* d_out, int out_size, void* d_ws, size_t ws_size,
                              hipStream_t stream) {
  const float* rgb   = (const float*)d_in[0];
  const float* y     = (const float*)d_in[1];
  const float* Wq    = (const float*)d_in[2];
  const float* bq    = (const float*)d_in[3];
  const float* Wk    = (const float*)d_in[4];
  const float* bk    = (const float*)d_in[5];
  const float* Wv    = (const float*)d_in[6];
  const float* bv    = (const float*)d_in[7];
  const float* alpha = (const float*)d_in[8];
  float* out = (float*)d_out;

  // ws layout (floats): qbuf 4.19M | kbuf 4.19M | part 2.10M | energy 32K |
  // wfT 32K | cf 512  => ~42.2 MB total
  float* ws     = (float*)d_ws;
  float* qbuf   = ws;
  float* kbuf   = qbuf + (size_t)B * CR * HW;
  float* part   = kbuf + (size_t)B * CR * HW;
  float* energy = part + (size_t)B * 4096 * SPLIT;
  float* wfT    = energy + (size_t)B * 4096;
  float* cfb    = wfT + (size_t)B * 4096;

  k_qkconv<<<dim3(HW / 512, B), 256, 0, stream>>>(rgb, Wq, bq, Wk, bk, qbuf, kbuf);
  k_energy<<<dim3(SPLIT, B), 128, 0, stream>>>(qbuf, kbuf, part);
  k_reduce<<<dim3((B * 4096) / 256), 256, 0, stream>>>(part, energy);
  k_attn_wf<<<dim3(B), 256, 0, stream>>>(energy, Wv, bv, alpha, wfT, cfb);
  k_out<<<dim3(HW / 128, B), 256, 0, stream>>>(y, wfT, cfb, out);
}

// Round 2
// 146.824 us; speedup vs baseline: 1.3274x; 1.3274x over previous
//
#include <hip/hip_runtime.h>

#define B 8
#define C 64
#define CR 8
#define HW 65536   // 256*256
#define HWF 8192   // HW/8 (folded spatial length)
#define SPLIT 64
#define CHUNK 128  // HWF / SPLIT

__device__ __forceinline__ void fma4(float4& a, float w, const float4& v) {
  a.x = fmaf(w, v.x, a.x); a.y = fmaf(w, v.y, a.y);
  a.z = fmaf(w, v.z, a.z); a.w = fmaf(w, v.w, a.w);
}

// ---------------- K1: fused q/k conv + energy partials -----------------------
// Block (sp, b): computes the 64x64 Gram partial over folded columns
// [sp*128, sp*128+128). Folded row c = o*8 + seg (reshape algebra: flat idx
// o*65536 + seg*8192 + n == c*8192 + n with c = o*8+seg). Each thread convs
// 4 positions of one seg (float4 rgb loads, 1KB/wave-instr, rgb read ONCE —
// no q/k HBM round-trip), writes swizzled LDS tiles, then 4x4 Gram tile.
__global__ __launch_bounds__(256) void k_conv_energy(
    const float* __restrict__ rgb,
    const float* __restrict__ Wq, const float* __restrict__ bq,
    const float* __restrict__ Wk, const float* __restrict__ bk,
    float* __restrict__ part) {
  __shared__ float qs[64 * 128];
  __shared__ float ks[64 * 128];
  __shared__ float wqs[64][8], wks[64][8];
  __shared__ float bqs[8], bks[8];
  int tid = threadIdx.x;
  for (int i = tid; i < 512; i += 256) {
    int o = i >> 6, ch = i & 63;
    wqs[ch][o] = Wq[i];
    wks[ch][o] = Wk[i];
  }
  if (tid < 8) { bqs[tid] = bq[tid]; bks[tid] = bk[tid]; }
  __syncthreads();

  int sp = blockIdx.x, b = blockIdx.y;
  int seg = tid >> 5, pl = tid & 31;   // seg 0..7, 32 float4-slots per chunk
  const float* rp = rgb + (size_t)b * C * HW + (size_t)seg * HWF + sp * CHUNK + pl * 4;

  float4 aq[8], ak[8];
#pragma unroll
  for (int o = 0; o < 8; ++o) {
    aq[o] = make_float4(bqs[o], bqs[o], bqs[o], bqs[o]);
    ak[o] = make_float4(bks[o], bks[o], bks[o], bks[o]);
  }
#pragma unroll 8
  for (int ch = 0; ch < 64; ++ch) {
    float4 v = *reinterpret_cast<const float4*>(rp + (size_t)ch * HW);
#pragma unroll
    for (int o = 0; o < 8; ++o) {
      fma4(aq[o], wqs[ch][o], v);
      fma4(ak[o], wks[ch][o], v);
    }
  }
  // write folded rows, XOR-swizzled float4 slot (same formula as Gram reads)
#pragma unroll
  for (int o = 0; o < 8; ++o) {
    int row = o * 8 + seg;
    int off = (row << 7) + ((pl ^ ((row >> 2) & 7)) << 2);
    *reinterpret_cast<float4*>(&qs[off]) = aq[o];
    *reinterpret_cast<float4*>(&ks[off]) = ak[o];
  }
  __syncthreads();

  // Gram: thread = (c4 0..15, d4 0..15) -> 4x4 output tile
  int c4 = tid >> 4, d4 = tid & 15;
  float acc[4][4];
#pragma unroll
  for (int i = 0; i < 4; ++i)
#pragma unroll
    for (int j = 0; j < 4; ++j) acc[i][j] = 0.f;

#pragma unroll 2
  for (int n4 = 0; n4 < 32; ++n4) {
    float4 qv[4], kv[4];
#pragma unroll
    for (int cc = 0; cc < 4; ++cc) {
      int r = c4 * 4 + cc;
      qv[cc] = *reinterpret_cast<const float4*>(
          &qs[(r << 7) + ((n4 ^ ((r >> 2) & 7)) << 2)]);
    }
#pragma unroll
    for (int dd = 0; dd < 4; ++dd) {
      int r = d4 * 4 + dd;
      kv[dd] = *reinterpret_cast<const float4*>(
          &ks[(r << 7) + ((n4 ^ ((r >> 2) & 7)) << 2)]);
    }
#pragma unroll
    for (int cc = 0; cc < 4; ++cc)
#pragma unroll
      for (int dd = 0; dd < 4; ++dd) {
        acc[cc][dd] = fmaf(qv[cc].x, kv[dd].x,
                      fmaf(qv[cc].y, kv[dd].y,
                      fmaf(qv[cc].z, kv[dd].z,
                      fmaf(qv[cc].w, kv[dd].w, acc[cc][dd]))));
      }
  }
  // part[b][sp][c*64+d] -> float4 over dd (d = d4*4+dd contiguous)
  float* pb = part + ((size_t)(b * SPLIT + sp) << 12);
#pragma unroll
  for (int cc = 0; cc < 4; ++cc) {
    int c = c4 * 4 + cc;
    *reinterpret_cast<float4*>(pb + c * 64 + d4 * 4) =
        make_float4(acc[cc][0], acc[cc][1], acc[cc][2], acc[cc][3]);
  }
}

// ---------------- K2: deterministic split reduction --------------------------
__global__ __launch_bounds__(256) void k_reduce(
    const float* __restrict__ part, float* __restrict__ energy) {
  int gid = blockIdx.x * 256 + threadIdx.x;   // b*4096 + (c*64+d)
  int b = gid >> 12, r = gid & 4095;
  const float* p = part + ((size_t)b << 18) + r;   // b*64*4096
  float s = 0.f;
#pragma unroll
  for (int sp = 0; sp < SPLIT; ++sp) s += p[(size_t)sp << 12];
  energy[gid] = s;
}

// ---------------- K3: softmax + fold into Wf = alpha*attn*Wv + I ------------
// softmax(max_d(e) - e) == exp(min_d(e) - e) / sum (the max-shift cancels).
// Writes WfT[b][ch][c] (transposed for K4's b128 reads) and cf = alpha*attn*bv.
__global__ __launch_bounds__(256) void k_attn_wf(
    const float* __restrict__ energy,
    const float* __restrict__ Wv, const float* __restrict__ bv,
    const float* __restrict__ alpha,
    float* __restrict__ wfT, float* __restrict__ cf) {
  __shared__ float es[64][65];
  __shared__ float at[64][65];
  __shared__ float wv[64 * 64];
  __shared__ float bvs[64];
  int tid = threadIdx.x;
  int b = blockIdx.x;
  const float* eb = energy + b * 4096;
  for (int i = tid; i < 4096; i += 256) {
    es[i >> 6][i & 63] = eb[i];
    wv[i] = Wv[i];
  }
  if (tid < 64) bvs[tid] = bv[tid];
  __syncthreads();
  float al = alpha[0];
  if (tid < 64) {
    int c = tid;
    float mn = es[c][0];
    for (int d = 1; d < 64; ++d) mn = fminf(mn, es[c][d]);
    float ssum = 0.f;
    for (int d = 0; d < 64; ++d) {
      float t = __expf(mn - es[c][d]);
      at[c][d] = t; ssum += t;
    }
    float inv = 1.f / ssum;   // ssum >= 1 (the min term is exp(0)), finite
    float cb = 0.f;
    for (int d = 0; d < 64; ++d) { at[c][d] *= inv; cb += at[c][d] * bvs[d]; }
    cf[b * 64 + c] = al * cb;
  }
  __syncthreads();
  for (int i = tid; i < 4096; i += 256) {
    int ch = i >> 6, c = i & 63;
    float s = 0.f;
    for (int d = 0; d < 64; ++d) s = fmaf(at[c][d], wv[d * 64 + ch], s);
    wfT[(size_t)b * 4096 + i] = al * s + (c == ch ? 1.f : 0.f);
  }
}

// ---------------- K4: streaming epilogue out = Wf*Y + cf ---------------------
// LDS-staged: 64ch x 128pos Y tile loaded with 8 coalesced float4/thread
// (1KB unique per wave-instr, 8 outstanding), then 8och x 4pos register tile
// fed from LDS. Kills the v1 latency problem (64 strided 16B loads/thread
// with 8x block-level redundancy through L1).
__global__ __launch_bounds__(256) void k_out(
    const float* __restrict__ y,
    const float* __restrict__ wfT, const float* __restrict__ cf,
    float* __restrict__ out) {
  __shared__ float yt[64 * 128];   // [ch][pos]
  __shared__ float wf[64 * 64];    // [ch][c]
  __shared__ float cfs[64];
  int tid = threadIdx.x;
  int b = blockIdx.y;
  int s0 = blockIdx.x * 128;
  const float* yb = y + (size_t)b * C * HW + s0;

  for (int i = tid; i < 4096; i += 256) wf[i] = wfT[((size_t)b << 12) + i];
  if (tid < 64) cfs[tid] = cf[b * 64 + tid];
#pragma unroll
  for (int j = 0; j < 8; ++j) {
    int i = tid + j * 256;
    int row = i >> 5, col = (i & 31) * 4;
    *reinterpret_cast<float4*>(&yt[row * 128 + col]) =
        *reinterpret_cast<const float4*>(yb + (size_t)row * HW + col);
  }
  __syncthreads();

  int pg = tid & 31, cg = tid >> 5;
  float4 acc[8];
#pragma unroll
  for (int cc = 0; cc < 8; ++cc) {
    float v = cfs[cg * 8 + cc];
    acc[cc] = make_float4(v, v, v, v);
  }
#pragma unroll 8
  for (int ch = 0; ch < 64; ++ch) {
    float4 yv = *reinterpret_cast<const float4*>(&yt[ch * 128 + pg * 4]);
    float4 w0 = *reinterpret_cast<const float4*>(&wf[ch * 64 + cg * 8]);
    float4 w1 = *reinterpret_cast<const float4*>(&wf[ch * 64 + cg * 8 + 4]);
    fma4(acc[0], w0.x, yv); fma4(acc[1], w0.y, yv);
    fma4(acc[2], w0.z, yv); fma4(acc[3], w0.w, yv);
    fma4(acc[4], w1.x, yv); fma4(acc[5], w1.y, yv);
    fma4(acc[6], w1.z, yv); fma4(acc[7], w1.w, yv);
  }
  float* ob = out + (size_t)b * C * HW + s0 + pg * 4;
#pragma unroll
  for (int cc = 0; cc < 8; ++cc)
    *reinterpret_cast<float4*>(ob + (size_t)(cg * 8 + cc) * HW) = acc[cc];
}

extern "C" void kernel_launch(void* const* d_in, const int* in_sizes, int n_in,
                              void* d_out, int out_size, void* d_ws, size_t ws_size,
                              hipStream_t stream) {
  const float* rgb   = (const float*)d_in[0];
  const float* y     = (const float*)d_in[1];
  const float* Wq    = (const float*)d_in[2];
  const float* bq    = (const float*)d_in[3];
  const float* Wk    = (const float*)d_in[4];
  const float* bk    = (const float*)d_in[5];
  const float* Wv    = (const float*)d_in[6];
  const float* bv    = (const float*)d_in[7];
  const float* alpha = (const float*)d_in[8];
  float* out = (float*)d_out;

  // ws layout (floats): part 2.10M (8.4MB) | energy 32K | wfT 32K | cf 512
  float* ws     = (float*)d_ws;
  float* part   = ws;
  float* energy = part + (size_t)B * SPLIT * 4096;
  float* wfT    = energy + (size_t)B * 4096;
  float* cfb    = wfT + (size_t)B * 4096;

  k_conv_energy<<<dim3(SPLIT, B), 256, 0, stream>>>(rgb, Wq, bq, Wk, bk, part);
  k_reduce<<<dim3((B * 4096) / 256), 256, 0, stream>>>(part, energy);
  k_attn_wf<<<dim3(B), 256, 0, stream>>>(energy, Wv, bv, alpha, wfT, cfb);
  k_out<<<dim3(HW / 128, B), 256, 0, stream>>>(y, wfT, cfb, out);
}